// Round 1
// baseline (1631.506 us; speedup 1.0000x reference)
//
#include <hip/hip_runtime.h>
#include <hip/hip_bf16.h>
#include <stdint.h>

#define B_    128
#define F_    4
#define V_    2048
#define D_    4096
#define DW    64      // D/64 bit-words
#define ITERS 20

typedef _Float16 half8 __attribute__((ext_vector_type(8)));
typedef float   floatx4 __attribute__((ext_vector_type(4)));

// ------------------------------------------------------------------
// Pack sign bits of a float array (values are exactly +-1.0) into u64
// words: bit d of word = 1 iff x[d] < 0.  Layout matches flat order.
// ------------------------------------------------------------------
__global__ void k_pack(const float* __restrict__ x, uint64_t* __restrict__ bits, int n) {
    int tid = blockIdx.x * blockDim.x + threadIdx.x;
    if (tid >= n) return;
    unsigned long long m = __ballot(x[tid] < 0.0f);
    if ((threadIdx.x & 63) == 0) bits[tid >> 6] = m;
}

// ------------------------------------------------------------------
// sim[b,f,v] via popcount.  new_est bits = in ^ xor(all est) ^ est_f.
// Writes sim/2 = 2048 - popcount  as exact fp16 (A operand of GEMM).
// grid: (vt=8, bt=8, f=4), block 256.  Each block: 256 v x 16 b.
// ------------------------------------------------------------------
__global__ void k_sim(const uint64_t* __restrict__ cb_bits,
                      const uint64_t* __restrict__ in_bits,
                      const uint64_t* __restrict__ est_bits,
                      _Float16* __restrict__ simf,
                      const int* __restrict__ flags, int iter) {
    if (iter > 0 && flags[iter - 1] == 0) return;   // converged: sim unchanged
    int vt = blockIdx.x, bt = blockIdx.y, f = blockIdx.z;
    int tid = threadIdx.x;
    __shared__ uint64_t nb[16][DW];
    #pragma unroll
    for (int j = 0; j < 4; ++j) {
        int idx = tid + j * 256;          // 1024 = 16 b * 64 words
        int bl = idx >> 6, w = idx & 63;
        int b = bt * 16 + bl;
        uint64_t e0 = est_bits[(b * F_ + 0) * DW + w];
        uint64_t e1 = est_bits[(b * F_ + 1) * DW + w];
        uint64_t e2 = est_bits[(b * F_ + 2) * DW + w];
        uint64_t e3 = est_bits[(b * F_ + 3) * DW + w];
        uint64_t ef = est_bits[(b * F_ + f) * DW + w];
        nb[bl][w] = in_bits[b * DW + w] ^ e0 ^ e1 ^ e2 ^ e3 ^ ef;
    }
    __syncthreads();
    int v = vt * 256 + tid;
    int acc[16];
    #pragma unroll
    for (int bl = 0; bl < 16; ++bl) acc[bl] = 2048;
    const uint64_t* cbrow = cb_bits + ((size_t)f * V_ + v) * DW;
    for (int w = 0; w < DW; ++w) {
        uint64_t cw = cbrow[w];
        #pragma unroll
        for (int bl = 0; bl < 16; ++bl)
            acc[bl] -= __popcll(nb[bl][w] ^ cw);
    }
    #pragma unroll
    for (int bl = 0; bl < 16; ++bl) {
        int b = bt * 16 + bl;
        simf[((size_t)f * B_ + b) * V_ + v] = (_Float16)acc[bl];   // exact: |acc|<=2048
    }
}

// ------------------------------------------------------------------
// C[b,d] = sum_v sim2[b,v] * cb[f][v,d]  (cb = +-1 from bits), fp16
// MFMA, fp32 accum (exact integers).  Epilogue: hardsign -> bit-pack
// into est_bits, diff-detect -> flags[iter].
// grid: (ntile=64, f=4), block 256 (4 waves), tile BM=128 BN=64 BK=64.
// ------------------------------------------------------------------
#define ASTR 72
#define BSTR 72
__global__ __launch_bounds__(256) void k_gemm(
        const _Float16* __restrict__ simf,
        const uint64_t* __restrict__ cb_bits,
        uint64_t* __restrict__ est_bits,
        int* __restrict__ flags, int iter) {
    if (iter > 0 && flags[iter - 1] == 0) return;   // converged: est unchanged
    int f = blockIdx.y;
    int nword = blockIdx.x;              // d-word index; n0 = nword*64
    int n0 = nword * 64;
    int tid = threadIdx.x;
    int wave = tid >> 6, lane = tid & 63;
    int lrow = lane & 15, lq = lane >> 4;

    __shared__ __align__(16) _Float16 As[128 * ASTR];
    __shared__ __align__(16) _Float16 Bs[64 * BSTR];
    __shared__ int bd;
    if (tid == 0) bd = 0;

    floatx4 acc[2][4] = {};
    const _Float16* Abase = simf + (size_t)f * B_ * V_;

    for (int kt = 0; kt < V_ / 64; ++kt) {
        // stage A: 128 rows x 64 k (fp16), coalesced 16B loads
        #pragma unroll
        for (int r = 0; r < 4; ++r) {
            int idx = r * 256 + tid;
            int row = idx >> 3, c = idx & 7;
            *(half8*)&As[row * ASTR + c * 8] =
                *(const half8*)&Abase[(size_t)row * V_ + kt * 64 + c * 8];
        }
        // stage B: 64 v x 64 d from bits, stored transposed Bs[n][k]
        {
            int vv = tid & 63, nc = tid >> 6;
            uint64_t wb = cb_bits[((size_t)f * V_ + kt * 64 + vv) * DW + nword];
            #pragma unroll
            for (int i = 0; i < 16; ++i) {
                int n = nc * 16 + i;
                Bs[n * BSTR + vv] = ((wb >> n) & 1) ? (_Float16)-1.0f : (_Float16)1.0f;
            }
        }
        __syncthreads();
        #pragma unroll
        for (int ks = 0; ks < 2; ++ks) {
            int kb = ks * 32 + lq * 8;
            half8 a0 = *(const half8*)&As[(wave * 32 + lrow) * ASTR + kb];
            half8 a1 = *(const half8*)&As[(wave * 32 + 16 + lrow) * ASTR + kb];
            #pragma unroll
            for (int nf = 0; nf < 4; ++nf) {
                half8 b = *(const half8*)&Bs[(nf * 16 + lrow) * BSTR + kb];
                acc[0][nf] = __builtin_amdgcn_mfma_f32_16x16x32_f16(a0, b, acc[0][nf], 0, 0, 0);
                acc[1][nf] = __builtin_amdgcn_mfma_f32_16x16x32_f16(a1, b, acc[1][nf], 0, 0, 0);
            }
        }
        __syncthreads();
    }

    // epilogue: sign -> LDS byte tile -> bit-pack word per row
    unsigned char* S = (unsigned char*)As;     // reuse LDS (safe after sync)
    #pragma unroll
    for (int mf = 0; mf < 2; ++mf)
        #pragma unroll
        for (int nf = 0; nf < 4; ++nf)
            #pragma unroll
            for (int r = 0; r < 4; ++r) {
                int row  = wave * 32 + mf * 16 + lq * 4 + r;   // C/D: row=quad*4+reg
                int coll = nf * 16 + lrow;                     // col=lane&15
                S[row * 64 + coll] = (acc[mf][nf][r] < 0.0f) ? 1 : 0;  // hardsign(0)=+1
            }
    __syncthreads();
    if (tid < 128) {
        uint64_t m = 0;
        #pragma unroll
        for (int i = 0; i < 64; ++i) m |= ((uint64_t)S[tid * 64 + i]) << i;
        size_t w = ((size_t)tid * F_ + f) * DW + nword;
        uint64_t old = est_bits[w];
        est_bits[w] = m;
        if (old != m) atomicOr(&bd, 1);
    }
    __syncthreads();
    if (tid == 0 && bd) atomicOr(&flags[iter], 1);
}

// ------------------------------------------------------------------
// Final: argmax_v |sim(est, cb)| with first-index tie-break (exact).
// grid: 512 blocks (b*F+f), block 256.
// ------------------------------------------------------------------
__global__ void k_argmax(const uint64_t* __restrict__ cb_bits,
                         const uint64_t* __restrict__ est_bits,
                         int* __restrict__ out) {
    int bf = blockIdx.x;
    int f = bf & 3;
    int tid = threadIdx.x;
    __shared__ uint64_t eb[DW];
    if (tid < DW) eb[tid] = est_bits[bf * DW + tid];
    __syncthreads();
    int bestm = -1, bestv = 0;
    for (int v = tid; v < V_; v += 256) {          // ascending v: first tie kept
        const uint64_t* cbrow = cb_bits + ((size_t)f * V_ + v) * DW;
        int pc = 0;
        for (int w = 0; w < DW; ++w) pc += __popcll(eb[w] ^ cbrow[w]);
        int m = 2048 - pc; if (m < 0) m = -m;      // |sim|/2
        if (m > bestm) { bestm = m; bestv = v; }
    }
    __shared__ int sm[256], sv[256];
    sm[tid] = bestm; sv[tid] = bestv;
    __syncthreads();
    for (int s = 128; s > 0; s >>= 1) {
        if (tid < s) {
            if (sm[tid + s] > sm[tid] ||
                (sm[tid + s] == sm[tid] && sv[tid + s] < sv[tid])) {
                sm[tid] = sm[tid + s]; sv[tid] = sv[tid + s];
            }
        }
        __syncthreads();
    }
    if (tid == 0) out[bf] = sv[0];
}

__global__ void k_final(const int* __restrict__ flags, int* __restrict__ out) {
    int k = ITERS - 1;
    for (int i = 0; i < ITERS; ++i) { if (flags[i] == 0) { k = i; break; } }
    out[B_ * F_] = k;
}

// ------------------------------------------------------------------
extern "C" void kernel_launch(void* const* d_in, const int* in_sizes, int n_in,
                              void* d_out, int out_size, void* d_ws, size_t ws_size,
                              hipStream_t stream) {
    const float* inputs = (const float*)d_in[0];   // (B, D)
    const float* inite  = (const float*)d_in[1];   // (B, F, D)
    const float* cb     = (const float*)d_in[2];   // (F, V, D)
    int* out = (int*)d_out;                        // 512 outcome + 1 k (int32)

    char* ws = (char*)d_ws;
    uint64_t* cb_bits  = (uint64_t*)ws;  ws += (size_t)F_ * V_ * DW * 8;   // 4 MiB
    uint64_t* est_bits = (uint64_t*)ws;  ws += (size_t)B_ * F_ * DW * 8;   // 256 KiB
    uint64_t* in_bits  = (uint64_t*)ws;  ws += (size_t)B_ * DW * 8;        // 64 KiB
    _Float16* simf     = (_Float16*)ws;  ws += (size_t)F_ * B_ * V_ * 2;   // 2 MiB
    int*      flags    = (int*)ws;       ws += 256;

    hipMemsetAsync(flags, 0, ITERS * sizeof(int), stream);
    k_pack<<<(F_ * V_ * D_) / 256, 256, 0, stream>>>(cb,     cb_bits,  F_ * V_ * D_);
    k_pack<<<(B_ * F_ * D_) / 256, 256, 0, stream>>>(inite,  est_bits, B_ * F_ * D_);
    k_pack<<<(B_ * D_) / 256,      256, 0, stream>>>(inputs, in_bits,  B_ * D_);

    for (int i = 0; i < ITERS; ++i) {
        k_sim<<<dim3(8, 8, 4),  256, 0, stream>>>(cb_bits, in_bits, est_bits, simf, flags, i);
        k_gemm<<<dim3(64, 4),   256, 0, stream>>>(simf, cb_bits, est_bits, flags, i);
    }
    k_argmax<<<B_ * F_, 256, 0, stream>>>(cb_bits, est_bits, out);
    k_final<<<1, 1, 0, stream>>>(flags, out);
}

// Round 2
// 1107.122 us; speedup vs baseline: 1.4736x; 1.4736x over previous
//
#include <hip/hip_runtime.h>
#include <hip/hip_bf16.h>
#include <stdint.h>

#define B_    128
#define F_    4
#define V_    2048
#define D_    4096
#define DW    64      // D/64 bit-words per (b,f) row
#define VW    32      // V/64 bit-words per d column
#define ITERS 20
#define NKT   16      // K tiles of 128 over V=2048

typedef _Float16 half8 __attribute__((ext_vector_type(8)));
typedef float   floatx4 __attribute__((ext_vector_type(4)));

// ------------------------------------------------------------------
// Pack sign bits of float array (+-1.0 exactly) into u64 words.
// ------------------------------------------------------------------
__global__ void k_pack(const float* __restrict__ x, uint64_t* __restrict__ bits, int n) {
    int tid = blockIdx.x * blockDim.x + threadIdx.x;
    if (tid >= n) return;
    unsigned long long m = __ballot(x[tid] < 0.0f);
    if ((threadIdx.x & 63) == 0) bits[tid >> 6] = m;
}

// ------------------------------------------------------------------
// Transpose cb_bits[f][v][dwords] -> cbT[f][d][vwords] (bit v of word).
// grid (vw=32, dwg=16, f=4), block 256 (4 waves, wave = one dw).
// ------------------------------------------------------------------
__global__ void k_packT(const uint64_t* __restrict__ cb_bits,
                        uint64_t* __restrict__ cbT) {
    int vw = blockIdx.x, dwg = blockIdx.y, f = blockIdx.z;
    int lane = threadIdx.x & 63;
    int dw = dwg * 4 + (threadIdx.x >> 6);
    uint64_t w = cb_bits[((size_t)f * V_ + vw * 64 + lane) * DW + dw];
    uint64_t r = 0;
    for (int d2 = 0; d2 < 64; ++d2) {
        uint64_t m = __ballot((unsigned)((w >> d2) & 1));
        if (lane == d2) r = m;
    }
    cbT[((size_t)f * D_ + dw * 64 + lane) * VW + vw] = r;
}

// ------------------------------------------------------------------
// sim[b,f,v] = 2048 - popcount(new_est ^ cb_row), exact fp16.
// new_est bits = in ^ e0^e1^e2^e3 ^ ef.
// grid (vt=8, bt=16, f=4) = 512 blocks, block 256.  8 b per block.
// ------------------------------------------------------------------
__global__ __launch_bounds__(256) void k_sim(
        const uint64_t* __restrict__ cb_bits,
        const uint64_t* __restrict__ in_bits,
        const uint64_t* __restrict__ est_bits,
        _Float16* __restrict__ simf,
        const int* __restrict__ flags, int iter) {
    if (iter > 0 && flags[iter - 1] == 0) return;
    int vt = blockIdx.x, bt = blockIdx.y, f = blockIdx.z;
    int tid = threadIdx.x;
    __shared__ __align__(16) uint64_t nb[8][DW];
    #pragma unroll
    for (int j = 0; j < 2; ++j) {
        int idx = tid + j * 256;          // 512 = 8 b * 64 words
        int bl = idx >> 6, w = idx & 63;
        int b = bt * 8 + bl;
        const uint64_t* e = est_bits + (size_t)b * F_ * DW;
        nb[bl][w] = in_bits[(size_t)b * DW + w] ^ e[0 * DW + w] ^ e[1 * DW + w]
                  ^ e[2 * DW + w] ^ e[3 * DW + w] ^ e[(size_t)f * DW + w];
    }
    __syncthreads();
    int v = vt * 256 + tid;
    int acc[8];
    #pragma unroll
    for (int bl = 0; bl < 8; ++bl) acc[bl] = 2048;
    const uint64_t* cbrow = cb_bits + ((size_t)f * V_ + v) * DW;
    for (int w = 0; w < DW; w += 2) {
        ulonglong2 c2 = *(const ulonglong2*)&cbrow[w];
        #pragma unroll
        for (int bl = 0; bl < 8; ++bl) {
            ulonglong2 n2 = *(const ulonglong2*)&nb[bl][w];
            acc[bl] -= __popcll(n2.x ^ c2.x) + __popcll(n2.y ^ c2.y);
        }
    }
    #pragma unroll
    for (int bl = 0; bl < 8; ++bl)
        simf[((size_t)f * B_ + bt * 8 + bl) * V_ + v] = (_Float16)acc[bl];
}

// ------------------------------------------------------------------
// C[b,d] = sum_v sim[b,v] * (+-1 from cbT bits); hardsign -> est_bits.
// BM=64 BN=64 BK=128; grid (nt=64, mt=2, f=4)=512 blocks, 256 thr.
// Wave tile 32m x 32n via 16x16x32 f16 MFMA (layout HW-verified R1).
// B bits preloaded to LDS once (XOR-swizzled); bytes decoded in regs.
// A tile prefetched to regs, XOR-swizzled LDS, conflict-free b128.
// ------------------------------------------------------------------
__global__ __launch_bounds__(256) void k_gemm(
        const _Float16* __restrict__ simf,
        const uint64_t* __restrict__ cbT,
        uint64_t* __restrict__ est_bits,
        int* __restrict__ flags, int iter) {
    if (iter > 0 && flags[iter - 1] == 0) return;
    int nt = blockIdx.x, mt = blockIdx.y, f = blockIdx.z;
    int m0 = mt * 64, n0 = nt * 64;
    int tid = threadIdx.x;
    int lane = tid & 63, wave = tid >> 6;
    int lrow = lane & 15, lq = lane >> 4;
    int wm = wave & 1, wn = wave >> 1;

    __shared__ __align__(16) uint64_t Bb[64 * VW];      // 16 KB, swizzled chunks
    __shared__ __align__(16) _Float16 As[64 * 128];     // 16 KB, swizzled chunks
    __shared__ int bd;
    if (tid == 0) bd = 0;

    // preload B bit-panel: 64 d-rows x 32 vwords, chunk(16B) cw' = cw ^ (dloc&15)
    const uint64_t* bsrc = cbT + ((size_t)f * D_ + n0) * VW;
    #pragma unroll
    for (int p = 0; p < 4; ++p) {
        int chunk = p * 256 + tid;                 // 1024 chunks
        int dloc = chunk >> 4, cw = chunk & 15;
        ulonglong2 val = *(const ulonglong2*)&bsrc[dloc * VW + cw * 2];
        *(ulonglong2*)&Bb[dloc * VW + ((cw ^ (dloc & 15)) * 2)] = val;
    }

    const _Float16* Ab = simf + (size_t)f * B_ * V_ + (size_t)m0 * V_;
    int arow = tid >> 4, acol = tid & 15;          // 16 rows x 16 chunks per pass
    half8 areg[4];
    #pragma unroll
    for (int p = 0; p < 4; ++p)
        areg[p] = *(const half8*)&Ab[(size_t)(p * 16 + arow) * V_ + acol * 8];

    floatx4 acc[2][2] = {};

    #pragma unroll 1
    for (int kt = 0; kt < NKT; ++kt) {
        __syncthreads();
        #pragma unroll
        for (int p = 0; p < 4; ++p)
            *(half8*)&As[(p * 16 + arow) * 128 + ((acol ^ arow) * 8)] = areg[p];
        if (kt + 1 < NKT) {
            #pragma unroll
            for (int p = 0; p < 4; ++p)   // prefetch next A tile (in flight over compute)
                areg[p] = *(const half8*)&Ab[(size_t)(p * 16 + arow) * V_ + (kt + 1) * 128 + acol * 8];
        }
        __syncthreads();

        ulonglong2 bw[2];
        #pragma unroll
        for (int nt2 = 0; nt2 < 2; ++nt2) {
            int dloc = wn * 32 + nt2 * 16 + lrow;
            bw[nt2] = *(const ulonglong2*)&Bb[dloc * VW + ((kt ^ (dloc & 15)) * 2)];
        }
        #pragma unroll
        for (int ks = 0; ks < 4; ++ks) {
            half8 af[2];
            #pragma unroll
            for (int mt2 = 0; mt2 < 2; ++mt2) {
                int row = wm * 32 + mt2 * 16 + lrow;
                af[mt2] = *(const half8*)&As[row * 128 + (((ks * 4 + lq) ^ lrow) * 8)];
            }
            half8 bfrag[2];
            #pragma unroll
            for (int nt2 = 0; nt2 < 2; ++nt2) {
                uint64_t w = (ks < 2) ? bw[nt2].x : bw[nt2].y;
                uint32_t byte = (uint32_t)(w >> ((((ks & 1) * 4 + lq)) * 8));
                union { uint32_t u[4]; half8 h; } bu;
                #pragma unroll
                for (int i = 0; i < 4; ++i) {
                    uint32_t lo = (byte << (15 - 2 * i)) & 0x8000u;       // bit 2i   -> sign lo
                    uint32_t hi = (byte << (30 - 2 * i)) & 0x80000000u;   // bit 2i+1 -> sign hi
                    bu.u[i] = 0x3C003C00u ^ (lo | hi);                    // {+1,+1} ^ signs
                }
                bfrag[nt2] = bu.h;
            }
            #pragma unroll
            for (int mt2 = 0; mt2 < 2; ++mt2)
                #pragma unroll
                for (int nt2 = 0; nt2 < 2; ++nt2)
                    acc[mt2][nt2] = __builtin_amdgcn_mfma_f32_16x16x32_f16(
                        af[mt2], bfrag[nt2], acc[mt2][nt2], 0, 0, 0);
        }
    }

    // epilogue: hardsign -> LDS bytes -> bit-pack 64-bit word per row
    __syncthreads();
    unsigned char* S = (unsigned char*)As;
    #pragma unroll
    for (int mt2 = 0; mt2 < 2; ++mt2)
        #pragma unroll
        for (int nt2 = 0; nt2 < 2; ++nt2)
            #pragma unroll
            for (int r = 0; r < 4; ++r) {
                int row = wm * 32 + mt2 * 16 + lq * 4 + r;   // C/D: row = quad*4+reg
                int col = wn * 32 + nt2 * 16 + lrow;         // col = lane&15
                S[row * 64 + col] = (acc[mt2][nt2][r] < 0.0f) ? 1 : 0;  // sign(0)=+1
            }
    __syncthreads();
    if (tid < 64) {
        const uint64_t* Sw = (const uint64_t*)S;
        uint64_t m = 0;
        #pragma unroll
        for (int j = 0; j < 8; ++j) {
            uint64_t w = Sw[tid * 8 + j];                    // 8 bytes of 0/1
            m |= ((w * 0x0102040810204080ull) >> 56) << (8 * j);  // exact bit-gather
        }
        size_t widx = ((size_t)(m0 + tid) * F_ + f) * DW + nt;
        uint64_t old = est_bits[widx];
        est_bits[widx] = m;
        if (old != m) atomicOr(&bd, 1);
    }
    __syncthreads();
    if (tid == 0 && bd) atomicOr(&flags[iter], 1);
}

// ------------------------------------------------------------------
// argmax_v |sim|: key = (|2048-pc|<<11) | (2047-v), atomicMax.
// grid (vt=8, bg=8, f=4) = 256 blocks; 16 b staged per block.
// ------------------------------------------------------------------
__global__ __launch_bounds__(256) void k_argmax(
        const uint64_t* __restrict__ cb_bits,
        const uint64_t* __restrict__ est_bits,
        int* __restrict__ keys) {
    int vt = blockIdx.x, bg = blockIdx.y, f = blockIdx.z;
    int tid = threadIdx.x, lane = tid & 63;
    __shared__ __align__(16) uint64_t eb[16][DW];
    #pragma unroll
    for (int j = 0; j < 4; ++j) {
        int idx = tid + j * 256;
        int bl = idx >> 6, w = idx & 63;
        eb[bl][w] = est_bits[((size_t)(bg * 16 + bl) * F_ + f) * DW + w];
    }
    __syncthreads();
    int v = vt * 256 + tid;
    const uint64_t* cbrow = cb_bits + ((size_t)f * V_ + v) * DW;
    int pc[16];
    #pragma unroll
    for (int bl = 0; bl < 16; ++bl) pc[bl] = 0;
    for (int w = 0; w < DW; w += 2) {
        ulonglong2 c2 = *(const ulonglong2*)&cbrow[w];
        #pragma unroll
        for (int bl = 0; bl < 16; ++bl) {
            ulonglong2 e2 = *(const ulonglong2*)&eb[bl][w];
            pc[bl] += __popcll(e2.x ^ c2.x) + __popcll(e2.y ^ c2.y);
        }
    }
    int key[16];
    #pragma unroll
    for (int bl = 0; bl < 16; ++bl) {
        int m = 2048 - pc[bl]; if (m < 0) m = -m;
        key[bl] = (m << 11) | (2047 - v);
    }
    #pragma unroll
    for (int s = 1; s < 64; s <<= 1)
        #pragma unroll
        for (int bl = 0; bl < 16; ++bl) {
            int o = __shfl_xor(key[bl], s, 64);
            if (o > key[bl]) key[bl] = o;
        }
    if (lane == 0)
        for (int bl = 0; bl < 16; ++bl)
            atomicMax(&keys[(size_t)(bg * 16 + bl) * F_ + f], key[bl]);
}

__global__ void k_final(const int* __restrict__ keys, const int* __restrict__ flags,
                        int* __restrict__ out) {
    int tid = blockIdx.x * blockDim.x + threadIdx.x;
    if (tid < B_ * F_) out[tid] = 2047 - (keys[tid] & 0x7FF);
    if (tid == 0) {
        int k = ITERS - 1;
        for (int i = 0; i < ITERS; ++i) if (flags[i] == 0) { k = i; break; }
        out[B_ * F_] = k;
    }
}

// ------------------------------------------------------------------
extern "C" void kernel_launch(void* const* d_in, const int* in_sizes, int n_in,
                              void* d_out, int out_size, void* d_ws, size_t ws_size,
                              hipStream_t stream) {
    const float* inputs = (const float*)d_in[0];   // (B, D)
    const float* inite  = (const float*)d_in[1];   // (B, F, D)
    const float* cb     = (const float*)d_in[2];   // (F, V, D)
    int* out = (int*)d_out;                        // 512 outcome + 1 k

    char* ws = (char*)d_ws;
    uint64_t* cb_bits  = (uint64_t*)ws;  ws += (size_t)F_ * V_ * DW * 8;   // 4 MiB
    uint64_t* cbT_bits = (uint64_t*)ws;  ws += (size_t)F_ * D_ * VW * 8;   // 4 MiB
    uint64_t* est_bits = (uint64_t*)ws;  ws += (size_t)B_ * F_ * DW * 8;   // 256 KiB
    uint64_t* in_bits  = (uint64_t*)ws;  ws += (size_t)B_ * DW * 8;        // 64 KiB
    _Float16* simf     = (_Float16*)ws;  ws += (size_t)F_ * B_ * V_ * 2;   // 2 MiB
    int*      flags    = (int*)ws;       ws += 32 * 4;
    int*      keys     = (int*)ws;       ws += B_ * F_ * 4;

    hipMemsetAsync(flags, 0, (32 + B_ * F_) * sizeof(int), stream);
    k_pack<<<(F_ * V_ * D_) / 256, 256, 0, stream>>>(cb,     cb_bits,  F_ * V_ * D_);
    k_pack<<<(B_ * F_ * D_) / 256, 256, 0, stream>>>(inite,  est_bits, B_ * F_ * D_);
    k_pack<<<(B_ * D_) / 256,      256, 0, stream>>>(inputs, in_bits,  B_ * D_);
    k_packT<<<dim3(32, 16, 4), 256, 0, stream>>>(cb_bits, cbT_bits);

    for (int i = 0; i < ITERS; ++i) {
        k_sim<<<dim3(8, 16, 4), 256, 0, stream>>>(cb_bits, in_bits, est_bits, simf, flags, i);
        k_gemm<<<dim3(64, 2, 4), 256, 0, stream>>>(simf, cbT_bits, est_bits, flags, i);
    }
    k_argmax<<<dim3(8, 8, 4), 256, 0, stream>>>(cb_bits, est_bits, keys);
    k_final<<<2, 256, 0, stream>>>(keys, flags, out);
}